// Round 4
// baseline (802.955 us; speedup 1.0000x reference)
//
#include <hip/hip_runtime.h>
#include <cstdint>
#include <cstddef>

#define TOK     8192
#define DIMD    1024
#define INTERD  1024
#define NEXP    16
#define SINTER  2048
#define CAP256  36864   // 32768 + 16*256 padding capacity
#define MAXT    144     // sum ceil(cnt_e/256) <= 128 + 16
#define HBLK    32

typedef __bf16 bf16_t;
typedef __bf16 bf16x8_t __attribute__((ext_vector_type(8)));
typedef __bf16 bf16x4_t __attribute__((ext_vector_type(4)));
typedef float  f32x4_t  __attribute__((ext_vector_type(4)));

// async global->LDS, 16B per lane; LDS dest is wave-uniform base + lane*16
__device__ __forceinline__ void gload_lds16(const bf16_t* g, bf16_t* l) {
  __builtin_amdgcn_global_load_lds((const __attribute__((address_space(1))) void*)g,
                                   (__attribute__((address_space(3))) void*)l,
                                   16, 0, 0);
}

// ---------------- init ----------------
__global__ void init_kernel(int* toklist, float* wtlist, int* tile_e, int* tile_rs) {
  int i = blockIdx.x * blockDim.x + threadIdx.x;
  if (i < CAP256) { toklist[i] = -1; wtlist[i] = 0.0f; }
  if (i < 512)    { tile_e[i] = -1; tile_rs[i] = 0; }
}

// ---------------- fp32 -> bf16 plain ----------------
__global__ void cvt_kernel(const float* __restrict__ in, bf16_t* __restrict__ out, int n4) {
  int stride = gridDim.x * blockDim.x;
  for (int i = blockIdx.x * blockDim.x + threadIdx.x; i < n4; i += stride) {
    float4 v = ((const float4*)in)[i];
    bf16x4_t o;
    o[0] = (bf16_t)v.x; o[1] = (bf16_t)v.y; o[2] = (bf16_t)v.z; o[3] = (bf16_t)v.w;
    ((bf16x4_t*)out)[i] = o;
  }
}

// ---------------- fp32 -> bf16 with 16-row W1/W3 interleave ----------------
// dst fused row f (within expert): p=f>>4, which=p&1, real=(p>>1)*16+(f&15)
__global__ void cvt_ileave(const float* __restrict__ s1, const float* __restrict__ s3,
                           bf16_t* __restrict__ dst, int total4, int esh) {
  int stride = gridDim.x * blockDim.x;
  int fmask = (1 << esh) - 1;
  for (int i = blockIdx.x * blockDim.x + threadIdx.x; i < total4; i += stride) {
    int k4 = i & 255;            // K=1024 -> K/4=256
    int fr = i >> 8;
    int e  = fr >> esh;
    int f  = fr & fmask;
    int p  = f >> 4, s = f & 15;
    int real = ((p >> 1) << 4) + s;
    size_t srow = ((size_t)e << (esh - 1)) + real;
    const float* src = ((p & 1) ? s3 : s1) + (srow << 10) + (k4 << 2);
    float4 v = *(const float4*)src;
    bf16x4_t o;
    o[0] = (bf16_t)v.x; o[1] = (bf16_t)v.y; o[2] = (bf16_t)v.z; o[3] = (bf16_t)v.w;
    ((bf16x4_t*)dst)[i] = o;
  }
}

// ---------------- gate: softmax -> top4 (one wave/token, no atomics) ----------------
__global__ __launch_bounds__(256)
void gate_kernel(const float* __restrict__ x, const float* __restrict__ gw,
                 int* __restrict__ tkidx, float* __restrict__ tkwt) {
  int wv = threadIdx.x >> 6, lane = threadIdx.x & 63;
  int t = blockIdx.x * 4 + wv;
  const float4* xp = (const float4*)(x + (size_t)t * DIMD + lane * 16);
  float4 xv[4];
#pragma unroll
  for (int i = 0; i < 4; ++i) xv[i] = xp[i];
  float sc[NEXP];
#pragma unroll
  for (int e = 0; e < NEXP; ++e) {
    const float4* wp = (const float4*)(gw + (size_t)e * DIMD + lane * 16);
    float s = 0.0f;
#pragma unroll
    for (int i = 0; i < 4; ++i) {
      float4 w = wp[i];
      s += xv[i].x * w.x + xv[i].y * w.y + xv[i].z * w.z + xv[i].w * w.w;
    }
    sc[e] = s;
  }
#pragma unroll
  for (int off = 32; off > 0; off >>= 1)
#pragma unroll
    for (int e = 0; e < NEXP; ++e)
      sc[e] += __shfl_xor(sc[e], off, 64);
  if (lane == 0) {
    float m = sc[0];
#pragma unroll
    for (int e = 1; e < NEXP; ++e) m = fmaxf(m, sc[e]);
    float p[NEXP], s = 0.0f;
#pragma unroll
    for (int e = 0; e < NEXP; ++e) { p[e] = __expf(sc[e] - m); s += p[e]; }
    float inv = 1.0f / s;
    unsigned used = 0;
    for (int k = 0; k < 4; ++k) {
      int best = 0; float bv = -1.0f;
#pragma unroll
      for (int e = 0; e < NEXP; ++e)
        if (!((used >> e) & 1u) && p[e] > bv) { bv = p[e]; best = e; }
      used |= 1u << best;
      tkidx[t * 4 + k] = best;
      tkwt[t * 4 + k] = bv * inv;
    }
  }
}

// ---------------- per-block histogram ----------------
__global__ __launch_bounds__(256)
void hist_kernel(const int* __restrict__ tkidx, int* __restrict__ blkhist) {
  __shared__ int h[NEXP];
  if (threadIdx.x < NEXP) h[threadIdx.x] = 0;
  __syncthreads();
  int4 v = ((const int4*)tkidx)[blockIdx.x * 256 + threadIdx.x];
  atomicAdd(&h[v.x], 1);
  atomicAdd(&h[v.y], 1);
  atomicAdd(&h[v.z], 1);
  atomicAdd(&h[v.w], 1);
  __syncthreads();
  if (threadIdx.x < NEXP) blkhist[blockIdx.x * NEXP + threadIdx.x] = h[threadIdx.x];
}

// ---------------- offsets + 256-granular tile table + scatter bases ----------------
__global__ void offs_kernel(const int* __restrict__ blkhist, int* __restrict__ offsets,
                            int* __restrict__ blkbase,
                            int* __restrict__ tile_e, int* __restrict__ tile_rs) {
  if (threadIdx.x != 0 || blockIdx.x != 0) return;
  int counts[NEXP];
  for (int e = 0; e < NEXP; ++e) {
    int s = 0;
    for (int b = 0; b < HBLK; ++b) s += blkhist[b * NEXP + e];
    counts[e] = s;
  }
  int off = 0, nt = 0;
  for (int e = 0; e < NEXP; ++e) {
    offsets[e] = off;
    int c = counts[e];
    int ntile = (c + 255) >> 8;
    for (int i = 0; i < ntile; ++i) { tile_e[nt] = e; tile_rs[nt] = off + (i << 8); ++nt; }
    off += ntile << 8;
  }
  offsets[NEXP] = off;
  for (int e = 0; e < NEXP; ++e) {
    int base = offsets[e];
    for (int b = 0; b < HBLK; ++b) {
      blkbase[b * NEXP + e] = base;
      base += blkhist[b * NEXP + e];
    }
  }
}

// ---------------- scatter (LDS cursors) ----------------
__global__ __launch_bounds__(256)
void scat_kernel(const int* __restrict__ tkidx, const float* __restrict__ tkwt,
                 const int* __restrict__ blkbase,
                 int* __restrict__ toklist, float* __restrict__ wtlist) {
  __shared__ int cur[NEXP];
  if (threadIdx.x < NEXP) cur[threadIdx.x] = blkbase[blockIdx.x * NEXP + threadIdx.x];
  __syncthreads();
  int idx = blockIdx.x * 256 + threadIdx.x;
  int4 v = ((const int4*)tkidx)[idx];
  float4 w = ((const float4*)tkwt)[idx];
  int p0 = atomicAdd(&cur[v.x], 1); toklist[p0] = idx; wtlist[p0] = w.x;
  int p1 = atomicAdd(&cur[v.y], 1); toklist[p1] = idx; wtlist[p1] = w.y;
  int p2 = atomicAdd(&cur[v.z], 1); toklist[p2] = idx; wtlist[p2] = w.z;
  int p3 = atomicAdd(&cur[v.w], 1); toklist[p3] = idx; wtlist[p3] = w.w;
}

// ============ 256-class GEMM, BK=64, SAFE counted-vmcnt double-buffer schedule ============
// Invariant: vmcnt(N) -> s_barrier -> ds_read. All waves' staging of tile kt is
// guaranteed landed before ANY wave reads it. End-of-iter barrier protects buffer reuse.
// EPI: 0 = dual silu epilogue -> H bf16 (B is 16-row interleaved [W1;W3])
//      1 = scatter atomicAdd into out (+wt*b2)
//      2 = dense write out (+b2)
#define SBAR __builtin_amdgcn_sched_barrier(0)

template <int BM, int BN, bool TABLE, int EPI>
__global__ __launch_bounds__(512, 2)
void gemm8p(const bf16_t* __restrict__ Ag, const bf16_t* __restrict__ Bw,
            const float* __restrict__ bias1, const float* __restrict__ bias3,
            void* __restrict__ Outp,
            const int* __restrict__ tile_e, const int* __restrict__ tile_rs,
            const int* __restrict__ toklist, const float* __restrict__ wtlist,
            int K, int ldOut, size_t strideB, int biasStride) {
  constexpr int AH = BM / 128, BH = BN / 128, HT = AH + BH;
  constexpr int MF = BM / 32, NF = BN / 64;   // per-wave frag counts (2M x 4N waves)
  __shared__ __align__(16) bf16_t lds[2 * HT * 8192];

  int rowstart, e = 0;
  if constexpr (TABLE) {
    e = tile_e[blockIdx.y];
    if (e < 0) return;
    rowstart = tile_rs[blockIdx.y];
  } else {
    rowstart = blockIdx.y * BM;
  }
  const bf16_t* Bwp = Bw + (TABLE ? (size_t)e * strideB : (size_t)0);
  const int boff = TABLE ? e * biasStride : 0;

  const int tid = threadIdx.x, lane = tid & 63, wv = tid >> 6;
  const int wm = wv >> 2, wn = wv & 3;
  const int xsw = (lane & 7) << 4;          // XOR swizzle (bits 4-6)
  const int klo = (lane >> 4) * 16;         // k-byte offset within MFMA step

  // ---- staging source pointers (pre-swizzled global: slot = (tid&7) ^ (row&7)) ----
  const bf16_t* srcp[2 * HT];
#pragma unroll
  for (int h = 0; h < AH; ++h)
#pragma unroll
    for (int j = 0; j < 2; ++j) {
      int rl = j * 64 + (tid >> 3);
      int grow = rowstart + h * 128 + rl;
      int slot = (tid & 7) ^ (rl & 7);
      long arow;
      if constexpr (TABLE && EPI == 0) {
        int t = toklist[grow];
        arow = (t < 0) ? 0 : t;
      } else {
        arow = grow;
      }
      srcp[h * 2 + j] = Ag + (size_t)arow * K + slot * 8;
    }
#pragma unroll
  for (int h = 0; h < BH; ++h)
#pragma unroll
    for (int j = 0; j < 2; ++j) {
      int rl = j * 64 + (tid >> 3);
      int grow = (int)blockIdx.x * BN + h * 128 + rl;
      int slot = (tid & 7) ^ (rl & 7);
      srcp[(AH + h) * 2 + j] = Bwp + (size_t)grow * K + slot * 8;
    }

#define STAGE(KT, BUF)                                                          \
  do {                                                                          \
    bf16_t* dst_ = (bf16_t*)lds + (BUF) * (HT * 8192);                          \
    _Pragma("unroll")                                                           \
    for (int h_ = 0; h_ < HT; ++h_) {                                           \
      _Pragma("unroll")                                                         \
      for (int j_ = 0; j_ < 2; ++j_)                                            \
        gload_lds16(srcp[h_ * 2 + j_] + (KT) * 64,                              \
                    dst_ + h_ * 8192 + j_ * 4096 + wv * 512);                   \
    }                                                                           \
  } while (0)

  // read fragments for MFMA k-step KS (0 or 1) from buffer base bufb (bytes)
#define READS(AF, BF, KS)                                                       \
  do {                                                                          \
    _Pragma("unroll")                                                           \
    for (int mi = 0; mi < MF; ++mi) {                                           \
      int rt_ = wm * (BM / 2) + mi * 16 + (lane & 15);                          \
      int hb_ = (rt_ >> 7) * 16384, rl_ = rt_ & 127;                            \
      AF[mi] = *(const bf16x8_t*)(bufb + hb_ +                                  \
        ((rl_ * 128 + (KS) * 64 + klo) ^ xsw));                                 \
    }                                                                           \
    _Pragma("unroll")                                                           \
    for (int ni = 0; ni < NF; ++ni) {                                           \
      int ct_ = wn * (BN / 4) + ni * 16 + (lane & 15);                          \
      int hb_ = (AH + (ct_ >> 7)) * 16384, rl_ = ct_ & 127;                     \
      BF[ni] = *(const bf16x8_t*)(bufb + hb_ +                                  \
        ((rl_ * 128 + (KS) * 64 + klo) ^ xsw));                                 \
    }                                                                           \
  } while (0)

#define DOMFMA(AF, BF)                                                          \
  do {                                                                          \
    _Pragma("unroll")                                                           \
    for (int mi = 0; mi < MF; ++mi)                                             \
      _Pragma("unroll")                                                         \
      for (int ni = 0; ni < NF; ++ni)                                           \
        acc[mi][ni] = __builtin_amdgcn_mfma_f32_16x16x32_bf16(                  \
            AF[mi], BF[ni], acc[mi][ni], 0, 0, 0);                              \
  } while (0)

  f32x4_t acc[MF][NF] = {};
  const int NTK = K >> 6;

  STAGE(0, 0);   // prologue: K-tile 0 -> buf0

  for (int kt = 0; kt < NTK; ++kt) {
    const char* bufb = (const char*)lds + (kt & 1) * (HT * 16384);
    if (kt + 1 < NTK) {
      STAGE(kt + 1, (kt + 1) & 1);
      SBAR;
      // own tile-kt staging landed (2*HT newest loads = tile kt+1 stay in flight)
      if constexpr (HT == 4) asm volatile("s_waitcnt vmcnt(8)" ::: "memory");
      else                   asm volatile("s_waitcnt vmcnt(6)" ::: "memory");
    } else {
      SBAR;
      asm volatile("s_waitcnt vmcnt(0)" ::: "memory");
    }
    SBAR;
    __builtin_amdgcn_s_barrier();   // ALL waves' tile-kt staging landed
    SBAR;
    {
      bf16x8_t a0[MF], b0[NF], a1[MF], b1[NF];
      READS(a0, b0, 0);
      READS(a1, b1, 1);
      __builtin_amdgcn_s_setprio(1);
      DOMFMA(a0, b0);
      DOMFMA(a1, b1);
      __builtin_amdgcn_s_setprio(0);
    }
    SBAR;
    __builtin_amdgcn_s_barrier();   // all reads of buf[kt&1] done before restage
  }

  // ---------------- epilogue ----------------
  if constexpr (EPI == 0) {
    constexpr int NR = BN / 2;  // real cols per tile (interleaved pairs)
    float b1v[NF / 2], b3v[NF / 2];
    int rcbase = (int)blockIdx.x * NR + wn * (NR / 4) + (lane & 15);
#pragma unroll
    for (int ni2 = 0; ni2 < NF / 2; ++ni2) {
      b1v[ni2] = bias1[boff + rcbase + ni2 * 16];
      b3v[ni2] = bias3[boff + rcbase + ni2 * 16];
    }
    bf16_t* Hout = (bf16_t*)Outp;
#pragma unroll
    for (int mi = 0; mi < MF; ++mi)
#pragma unroll
      for (int rg = 0; rg < 4; ++rg) {
        int rt = wm * (BM / 2) + mi * 16 + ((lane >> 4) << 2) + rg;
        int grow = rowstart + rt;
        float wt = 1.0f;
        if constexpr (TABLE) wt = wtlist[grow];
        size_t ob = (size_t)grow * ldOut + rcbase;
#pragma unroll
        for (int ni2 = 0; ni2 < NF / 2; ++ni2) {
          float v1 = acc[mi][2 * ni2][rg] + b1v[ni2];
          float v3 = acc[mi][2 * ni2 + 1][rg] + b3v[ni2];
          float sg = v1 / (1.0f + __expf(-v1));
          Hout[ob + ni2 * 16] = (bf16_t)(sg * v3 * wt);
        }
      }
  } else {
    float bv[NF];
    int colbase = (int)blockIdx.x * BN + wn * (BN / 4) + (lane & 15);
#pragma unroll
    for (int ni = 0; ni < NF; ++ni) bv[ni] = bias1[boff + colbase + ni * 16];
    float* Fout = (float*)Outp;
#pragma unroll
    for (int mi = 0; mi < MF; ++mi)
#pragma unroll
      for (int rg = 0; rg < 4; ++rg) {
        int rt = wm * (BM / 2) + mi * 16 + ((lane >> 4) << 2) + rg;
        int grow = rowstart + rt;
        if constexpr (EPI == 1) {
          int t = toklist[grow];
          float wt = wtlist[grow];
          if (t >= 0) {
            size_t ob = (size_t)t * ldOut + colbase;
#pragma unroll
            for (int ni = 0; ni < NF; ++ni)
              atomicAdd(&Fout[ob + ni * 16], acc[mi][ni][rg] + wt * bv[ni]);
          }
        } else {
          size_t ob = (size_t)grow * ldOut + colbase;
#pragma unroll
          for (int ni = 0; ni < NF; ++ni)
            Fout[ob + ni * 16] = acc[mi][ni][rg] + bv[ni];
        }
      }
  }
#undef STAGE
#undef READS
#undef DOMFMA
}

// ---------------- host ----------------
extern "C" void kernel_launch(void* const* d_in, const int* in_sizes, int n_in,
                              void* d_out, int out_size, void* d_ws, size_t ws_size,
                              hipStream_t stream) {
  const float* x   = (const float*)d_in[0];
  const float* gw  = (const float*)d_in[1];
  const float* ew1 = (const float*)d_in[2];
  const float* eb1 = (const float*)d_in[3];
  const float* ew2 = (const float*)d_in[4];
  const float* eb2 = (const float*)d_in[5];
  const float* ew3 = (const float*)d_in[6];
  const float* eb3 = (const float*)d_in[7];
  const float* sw1 = (const float*)d_in[8];
  const float* sb1 = (const float*)d_in[9];
  const float* sw2 = (const float*)d_in[10];
  const float* sb2 = (const float*)d_in[11];
  const float* sw3 = (const float*)d_in[12];
  const float* sb3 = (const float*)d_in[13];
  float* out = (float*)d_out;
  (void)ws_size;

  char* ws = (char*)d_ws;
  size_t off = 0;
  auto alloc = [&](size_t bytes) -> void* {
    off = (off + 255) & ~(size_t)255;
    void* p = ws + off;
    off += bytes;
    return p;
  };

  bf16_t* xb    = (bf16_t*)alloc((size_t)TOK * DIMD * 2);
  bf16_t* ew13i = (bf16_t*)alloc((size_t)NEXP * 2 * INTERD * DIMD * 2);
  bf16_t* ew2b  = (bf16_t*)alloc((size_t)NEXP * DIMD * INTERD * 2);
  bf16_t* sw13i = (bf16_t*)alloc((size_t)2 * SINTER * DIMD * 2);
  bf16_t* sw2b  = (bf16_t*)alloc((size_t)DIMD * SINTER * 2);
  // H union: shared Hs (8192x2048) and routed Hg (36864x1024) used in disjoint windows
  bf16_t* Hun   = (bf16_t*)alloc((size_t)CAP256 * INTERD * 2);
  bf16_t* Hs    = Hun;
  bf16_t* Hg    = Hun;
  int*   toklist = (int*)alloc(CAP256 * 4);
  float* wtlist  = (float*)alloc(CAP256 * 4);
  int*   offsets = (int*)alloc((NEXP + 1) * 4);
  int*   blkhist = (int*)alloc(HBLK * NEXP * 4);
  int*   blkbase = (int*)alloc(HBLK * NEXP * 4);
  int*   tile_e  = (int*)alloc(512 * 4);
  int*   tile_rs = (int*)alloc(512 * 4);
  int*   tkidx   = (int*)alloc((size_t)TOK * 4 * 4);
  float* tkwt    = (float*)alloc((size_t)TOK * 4 * 4);

  init_kernel<<<(CAP256 + 255) / 256, 256, 0, stream>>>(toklist, wtlist, tile_e, tile_rs);

  cvt_kernel<<<2048, 256, 0, stream>>>(x,   xb,   TOK * DIMD / 4);
  cvt_kernel<<<2048, 256, 0, stream>>>(ew2, ew2b, NEXP * DIMD * INTERD / 4);
  cvt_kernel<<<512,  256, 0, stream>>>(sw2, sw2b, DIMD * SINTER / 4);
  cvt_ileave<<<2048, 256, 0, stream>>>(ew1, ew3, ew13i, NEXP * 2 * INTERD * DIMD / 4, 11);
  cvt_ileave<<<1024, 256, 0, stream>>>(sw1, sw3, sw13i, 2 * SINTER * DIMD / 4, 12);

  gate_kernel<<<TOK / 4, 256, 0, stream>>>(x, gw, tkidx, tkwt);
  hist_kernel<<<HBLK, 256, 0, stream>>>(tkidx, blkhist);
  offs_kernel<<<1, 64, 0, stream>>>(blkhist, offsets, blkbase, tile_e, tile_rs);
  scat_kernel<<<HBLK, 256, 0, stream>>>(tkidx, tkwt, blkbase, toklist, wtlist);

  // shared expert: H = silu(x sw1^T + sb1)*(x sw3^T + sb3); out = H sw2^T + sb2
  gemm8p<256, 256, false, 0><<<dim3(2 * SINTER / 256, TOK / 256), 512, 0, stream>>>(
      xb, sw13i, sb1, sb3, Hs, nullptr, nullptr, nullptr, nullptr,
      DIMD, SINTER, 0, 0);
  gemm8p<128, 256, false, 2><<<dim3(DIMD / 256, TOK / 128), 512, 0, stream>>>(
      Hs, sw2b, sb2, nullptr, out, nullptr, nullptr, nullptr, nullptr,
      SINTER, DIMD, 0, 0);

  // routed experts (grouped 256-row tiles; H pre-scaled by route weight)
  gemm8p<256, 256, true, 0><<<dim3(2 * INTERD / 256, MAXT), 512, 0, stream>>>(
      xb, ew13i, eb1, eb3, Hg, tile_e, tile_rs, toklist, wtlist,
      DIMD, INTERD, (size_t)2 * INTERD * DIMD, INTERD);
  gemm8p<256, 256, true, 1><<<dim3(DIMD / 256, MAXT), 512, 0, stream>>>(
      Hg, ew2b, eb2, nullptr, out, tile_e, tile_rs, toklist, wtlist,
      INTERD, DIMD, (size_t)DIMD * INTERD, DIMD);
}

// Round 5
// 626.581 us; speedup vs baseline: 1.2815x; 1.2815x over previous
//
#include <hip/hip_runtime.h>
#include <cstdint>
#include <cstddef>

#define TOK     8192
#define DIMD    1024
#define INTERD  1024
#define NEXP    16
#define SINTER  2048
#define CAP256  36864   // 32768 + 16*256 padding capacity
#define MAXT    144     // sum ceil(cnt_e/256) <= 128 + 16
#define HBLK    32

typedef __bf16 bf16_t;
typedef __bf16 bf16x8_t __attribute__((ext_vector_type(8)));
typedef __bf16 bf16x4_t __attribute__((ext_vector_type(4)));
typedef float  f32x4_t  __attribute__((ext_vector_type(4)));

// async global->LDS, 16B per lane; LDS dest is wave-uniform base + lane*16
__device__ __forceinline__ void gload_lds16(const bf16_t* g, bf16_t* l) {
  __builtin_amdgcn_global_load_lds((const __attribute__((address_space(1))) void*)g,
                                   (__attribute__((address_space(3))) void*)l,
                                   16, 0, 0);
}

// ---------------- init ----------------
__global__ void init_kernel(int* toklist, float* wtlist, int* tile_e, int* tile_rs) {
  int i = blockIdx.x * blockDim.x + threadIdx.x;
  if (i < CAP256) { toklist[i] = -1; wtlist[i] = 0.0f; }
  if (i < 512)    { tile_e[i] = -1; tile_rs[i] = 0; }
}

// ---------------- fp32 -> bf16 plain ----------------
__global__ void cvt_kernel(const float* __restrict__ in, bf16_t* __restrict__ out, int n4) {
  int stride = gridDim.x * blockDim.x;
  for (int i = blockIdx.x * blockDim.x + threadIdx.x; i < n4; i += stride) {
    float4 v = ((const float4*)in)[i];
    bf16x4_t o;
    o[0] = (bf16_t)v.x; o[1] = (bf16_t)v.y; o[2] = (bf16_t)v.z; o[3] = (bf16_t)v.w;
    ((bf16x4_t*)out)[i] = o;
  }
}

// ---------------- fp32 -> bf16 with 16-row W1/W3 interleave ----------------
__global__ void cvt_ileave(const float* __restrict__ s1, const float* __restrict__ s3,
                           bf16_t* __restrict__ dst, int total4, int esh) {
  int stride = gridDim.x * blockDim.x;
  int fmask = (1 << esh) - 1;
  for (int i = blockIdx.x * blockDim.x + threadIdx.x; i < total4; i += stride) {
    int k4 = i & 255;            // K=1024 -> K/4=256
    int fr = i >> 8;
    int e  = fr >> esh;
    int f  = fr & fmask;
    int p  = f >> 4, s = f & 15;
    int real = ((p >> 1) << 4) + s;
    size_t srow = ((size_t)e << (esh - 1)) + real;
    const float* src = ((p & 1) ? s3 : s1) + (srow << 10) + (k4 << 2);
    float4 v = *(const float4*)src;
    bf16x4_t o;
    o[0] = (bf16_t)v.x; o[1] = (bf16_t)v.y; o[2] = (bf16_t)v.z; o[3] = (bf16_t)v.w;
    ((bf16x4_t*)dst)[i] = o;
  }
}

// ---------------- gate: softmax -> top4 (one wave/token, no atomics) ----------------
__global__ __launch_bounds__(256)
void gate_kernel(const float* __restrict__ x, const float* __restrict__ gw,
                 int* __restrict__ tkidx, float* __restrict__ tkwt) {
  int wv = threadIdx.x >> 6, lane = threadIdx.x & 63;
  int t = blockIdx.x * 4 + wv;
  const float4* xp = (const float4*)(x + (size_t)t * DIMD + lane * 16);
  float4 xv[4];
#pragma unroll
  for (int i = 0; i < 4; ++i) xv[i] = xp[i];
  float sc[NEXP];
#pragma unroll
  for (int e = 0; e < NEXP; ++e) {
    const float4* wp = (const float4*)(gw + (size_t)e * DIMD + lane * 16);
    float s = 0.0f;
#pragma unroll
    for (int i = 0; i < 4; ++i) {
      float4 w = wp[i];
      s += xv[i].x * w.x + xv[i].y * w.y + xv[i].z * w.z + xv[i].w * w.w;
    }
    sc[e] = s;
  }
#pragma unroll
  for (int off = 32; off > 0; off >>= 1)
#pragma unroll
    for (int e = 0; e < NEXP; ++e)
      sc[e] += __shfl_xor(sc[e], off, 64);
  if (lane == 0) {
    float m = sc[0];
#pragma unroll
    for (int e = 1; e < NEXP; ++e) m = fmaxf(m, sc[e]);
    float p[NEXP], s = 0.0f;
#pragma unroll
    for (int e = 0; e < NEXP; ++e) { p[e] = __expf(sc[e] - m); s += p[e]; }
    float inv = 1.0f / s;
    unsigned used = 0;
    for (int k = 0; k < 4; ++k) {
      int best = 0; float bv = -1.0f;
#pragma unroll
      for (int e = 0; e < NEXP; ++e)
        if (!((used >> e) & 1u) && p[e] > bv) { bv = p[e]; best = e; }
      used |= 1u << best;
      tkidx[t * 4 + k] = best;
      tkwt[t * 4 + k] = bv * inv;
    }
  }
}

// ---------------- per-block histogram ----------------
__global__ __launch_bounds__(256)
void hist_kernel(const int* __restrict__ tkidx, int* __restrict__ blkhist) {
  __shared__ int h[NEXP];
  if (threadIdx.x < NEXP) h[threadIdx.x] = 0;
  __syncthreads();
  int4 v = ((const int4*)tkidx)[blockIdx.x * 256 + threadIdx.x];
  atomicAdd(&h[v.x], 1);
  atomicAdd(&h[v.y], 1);
  atomicAdd(&h[v.z], 1);
  atomicAdd(&h[v.w], 1);
  __syncthreads();
  if (threadIdx.x < NEXP) blkhist[blockIdx.x * NEXP + threadIdx.x] = h[threadIdx.x];
}

// ---------------- offsets + 256-granular tile table + scatter bases ----------------
__global__ void offs_kernel(const int* __restrict__ blkhist, int* __restrict__ offsets,
                            int* __restrict__ blkbase,
                            int* __restrict__ tile_e, int* __restrict__ tile_rs) {
  if (threadIdx.x != 0 || blockIdx.x != 0) return;
  int counts[NEXP];
  for (int e = 0; e < NEXP; ++e) {
    int s = 0;
    for (int b = 0; b < HBLK; ++b) s += blkhist[b * NEXP + e];
    counts[e] = s;
  }
  int off = 0, nt = 0;
  for (int e = 0; e < NEXP; ++e) {
    offsets[e] = off;
    int c = counts[e];
    int ntile = (c + 255) >> 8;
    for (int i = 0; i < ntile; ++i) { tile_e[nt] = e; tile_rs[nt] = off + (i << 8); ++nt; }
    off += ntile << 8;
  }
  offsets[NEXP] = off;
  for (int e = 0; e < NEXP; ++e) {
    int base = offsets[e];
    for (int b = 0; b < HBLK; ++b) {
      blkbase[b * NEXP + e] = base;
      base += blkhist[b * NEXP + e];
    }
  }
}

// ---------------- scatter (LDS cursors) ----------------
__global__ __launch_bounds__(256)
void scat_kernel(const int* __restrict__ tkidx, const float* __restrict__ tkwt,
                 const int* __restrict__ blkbase,
                 int* __restrict__ toklist, float* __restrict__ wtlist) {
  __shared__ int cur[NEXP];
  if (threadIdx.x < NEXP) cur[threadIdx.x] = blkbase[blockIdx.x * NEXP + threadIdx.x];
  __syncthreads();
  int idx = blockIdx.x * 256 + threadIdx.x;
  int4 v = ((const int4*)tkidx)[idx];
  float4 w = ((const float4*)tkwt)[idx];
  int p0 = atomicAdd(&cur[v.x], 1); toklist[p0] = idx; wtlist[p0] = w.x;
  int p1 = atomicAdd(&cur[v.y], 1); toklist[p1] = idx; wtlist[p1] = w.y;
  int p2 = atomicAdd(&cur[v.z], 1); toklist[p2] = idx; wtlist[p2] = w.z;
  int p3 = atomicAdd(&cur[v.w], 1); toklist[p3] = idx; wtlist[p3] = w.w;
}

// ============ 256x256 GEMM, BK=64, 4-phase/K-tile 8-phase-style schedule ============
// Phases per K-tile: (ks0,Ah0)(ks0,Ah1)(ks1,Ah0)(ks1,Ah1); 16 MFMA each.
// Staging for tile t+1: {Ah0,Bh0,Bh1}@ph0 (vmcnt(6) drains tile t's Ah1),
// {Ah1}@ph1, vmcnt(2)@ph3 (drains t+1's first 3 half-tiles, leaves Ah1 in flight).
// Every wait precedes a barrier; ds_reads follow the publishing barrier.
#define SBAR __builtin_amdgcn_sched_barrier(0)

template <bool TABLE, int EPI>
__global__ __launch_bounds__(512, 2)
void gemm8p(const bf16_t* __restrict__ Ag, const bf16_t* __restrict__ Bw,
            const float* __restrict__ bias1, const float* __restrict__ bias3,
            void* __restrict__ Outp,
            const int* __restrict__ tile_e, const int* __restrict__ tile_rs,
            const int* __restrict__ toklist, const float* __restrict__ wtlist,
            int K, int ldOut, size_t strideB, int biasStride) {
  constexpr int BM = 256, BN = 256;
  __shared__ __align__(16) bf16_t lds[65536];   // 2 bufs x (A 16K elems + B 16K elems)

  int rowstart, e = 0;
  if constexpr (TABLE) {
    e = tile_e[blockIdx.y];
    if (e < 0) return;
    rowstart = tile_rs[blockIdx.y];
  } else {
    rowstart = blockIdx.y * BM;
  }
  const bf16_t* Bwp = Bw + (TABLE ? (size_t)e * strideB : (size_t)0);
  const int boff = TABLE ? e * biasStride : 0;

  const int tid = threadIdx.x, lane = tid & 63, wv = tid >> 6;
  const int wm = wv >> 2, wn = wv & 3;
  const int xsw = (lane & 7) << 4;          // XOR swizzle (byte bits 4-6)
  const int klo = (lane >> 4) * 16;         // k-byte offset within MFMA step

  // ---- staging source pointers; half-tile h of A/B, load j ----
  const bf16_t* srcp[8];
#pragma unroll
  for (int h = 0; h < 2; ++h)
#pragma unroll
    for (int j = 0; j < 2; ++j) {
      int idx = tid + j * 512;
      int r = h * 128 + (idx >> 3);               // row within 256-row tile
      int slot = (idx & 7) ^ ((idx >> 3) & 7);    // pre-swizzled global slot
      long arow;
      if constexpr (TABLE && EPI == 0) {
        int t = toklist[rowstart + r];
        arow = (t < 0) ? 0 : t;
      } else {
        arow = rowstart + r;
      }
      srcp[h * 2 + j] = Ag + (size_t)arow * K + slot * 8;
      int br = (int)blockIdx.x * BN + r;
      srcp[4 + h * 2 + j] = Bwp + (size_t)br * K + slot * 8;
    }

  // stage one half-tile (2 loads). HB=0: A-half H; HB=1: B-half H.
#define STG_HT(HB, H, NB, KT)                                                   \
  do {                                                                          \
    bf16_t* d_ = (bf16_t*)lds + (NB) * 32768 + (HB) * 16384 + (H) * 8192 + tid * 8; \
    gload_lds16(srcp[(HB) * 4 + (H) * 2 + 0] + (KT) * 64, d_);                  \
    gload_lds16(srcp[(HB) * 4 + (H) * 2 + 1] + (KT) * 64, d_ + 4096);           \
  } while (0)

  f32x4_t acc[8][4] = {};
  bf16x8_t bfr[4];

  // PHASE(KS, MH, STG, WT): STG 0=none 1={Ah0,Bh0,Bh1} 2={Ah1};
  // WT 0=none 1=vmcnt(6) 2=vmcnt(2) 3=vmcnt(0)
#define PHASE(KS, MH, STG, WT, BUFB, NB, KT1)                                   \
  do {                                                                          \
    bf16x8_t afr[4];                                                            \
    _Pragma("unroll")                                                           \
    for (int q = 0; q < 4; ++q) {                                               \
      int rl = wm * 64 + q * 16 + (lane & 15);                                  \
      afr[q] = *(const bf16x8_t*)((BUFB) + (MH) * 16384 +                       \
                 ((rl * 128 + (KS) * 64 + klo) ^ xsw));                         \
    }                                                                           \
    if ((MH) == 0) {                                                            \
      _Pragma("unroll")                                                         \
      for (int ni = 0; ni < 4; ++ni) {                                          \
        int ct = wn * 64 + ni * 16 + (lane & 15);                               \
        bfr[ni] = *(const bf16x8_t*)((BUFB) + 32768 + (ct >> 7) * 16384 +       \
                   (((ct & 127) * 128 + (KS) * 64 + klo) ^ xsw));               \
      }                                                                         \
    }                                                                           \
    if ((STG) == 1) {                                                           \
      STG_HT(0, 0, NB, KT1);                                                    \
      STG_HT(1, 0, NB, KT1);                                                    \
      STG_HT(1, 1, NB, KT1);                                                    \
    } else if ((STG) == 2) {                                                    \
      STG_HT(0, 1, NB, KT1);                                                    \
    }                                                                           \
    SBAR;                                                                       \
    if ((WT) == 1) asm volatile("s_waitcnt vmcnt(6)" ::: "memory");             \
    else if ((WT) == 2) asm volatile("s_waitcnt vmcnt(2)" ::: "memory");        \
    else if ((WT) == 3) asm volatile("s_waitcnt vmcnt(0)" ::: "memory");        \
    SBAR;                                                                       \
    __builtin_amdgcn_s_barrier();                                               \
    asm volatile("s_waitcnt lgkmcnt(0)" ::: "memory");                          \
    SBAR;                                                                       \
    __builtin_amdgcn_s_setprio(1);                                              \
    _Pragma("unroll")                                                           \
    for (int q = 0; q < 4; ++q)                                                 \
      _Pragma("unroll")                                                         \
      for (int ni = 0; ni < 4; ++ni)                                            \
        acc[(MH) * 4 + q][ni] = __builtin_amdgcn_mfma_f32_16x16x32_bf16(        \
            afr[q], bfr[ni], acc[(MH) * 4 + q][ni], 0, 0, 0);                   \
    __builtin_amdgcn_s_setprio(0);                                              \
    __builtin_amdgcn_s_barrier();                                               \
    SBAR;                                                                       \
  } while (0)

  const int NTK = K >> 6;

  // prologue: stage full tile 0 into buf0, drain, publish
  STG_HT(0, 0, 0, 0);
  STG_HT(1, 0, 0, 0);
  STG_HT(1, 1, 0, 0);
  STG_HT(0, 1, 0, 0);
  SBAR;
  asm volatile("s_waitcnt vmcnt(0)" ::: "memory");
  SBAR;
  __builtin_amdgcn_s_barrier();
  SBAR;

  for (int kt = 0; kt < NTK - 1; ++kt) {
    const char* bufb = (const char*)lds + (kt & 1) * 65536;
    int nb = (kt + 1) & 1, k1 = kt + 1;
    PHASE(0, 0, 1, 1, bufb, nb, k1);
    PHASE(0, 1, 2, 0, bufb, nb, k1);
    PHASE(1, 0, 0, 0, bufb, nb, k1);
    PHASE(1, 1, 0, 2, bufb, nb, k1);
  }
  {
    const char* bufb = (const char*)lds + ((NTK - 1) & 1) * 65536;
    PHASE(0, 0, 0, 3, bufb, 0, 0);
    PHASE(0, 1, 0, 0, bufb, 0, 0);
    PHASE(1, 0, 0, 0, bufb, 0, 0);
    PHASE(1, 1, 0, 0, bufb, 0, 0);
  }

  // ---------------- epilogue ----------------
  if constexpr (EPI == 0) {
    float b1v[2], b3v[2];
    int rcbase = (int)blockIdx.x * 128 + wn * 32 + (lane & 15);
#pragma unroll
    for (int ni2 = 0; ni2 < 2; ++ni2) {
      b1v[ni2] = bias1[boff + rcbase + ni2 * 16];
      b3v[ni2] = bias3[boff + rcbase + ni2 * 16];
    }
    bf16_t* Hout = (bf16_t*)Outp;
#pragma unroll
    for (int mi = 0; mi < 8; ++mi)
#pragma unroll
      for (int rg = 0; rg < 4; ++rg) {
        int Rb = (mi < 4) ? (wm * 64 + mi * 16) : (128 + wm * 64 + (mi - 4) * 16);
        int rt = Rb + ((lane >> 4) << 2) + rg;
        int grow = rowstart + rt;
        float wt = 1.0f;
        if constexpr (TABLE) wt = wtlist[grow];
        size_t ob = (size_t)grow * ldOut + rcbase;
#pragma unroll
        for (int ni2 = 0; ni2 < 2; ++ni2) {
          float v1 = acc[mi][2 * ni2][rg] + b1v[ni2];
          float v3 = acc[mi][2 * ni2 + 1][rg] + b3v[ni2];
          float sg = v1 / (1.0f + __expf(-v1));
          Hout[ob + ni2 * 16] = (bf16_t)(sg * v3 * wt);
        }
      }
  } else {
    float bv[4];
    int colbase = (int)blockIdx.x * BN + wn * 64 + (lane & 15);
#pragma unroll
    for (int ni = 0; ni < 4; ++ni) bv[ni] = bias1[boff + colbase + ni * 16];
    float* Fout = (float*)Outp;
#pragma unroll
    for (int mi = 0; mi < 8; ++mi)
#pragma unroll
      for (int rg = 0; rg < 4; ++rg) {
        int Rb = (mi < 4) ? (wm * 64 + mi * 16) : (128 + wm * 64 + (mi - 4) * 16);
        int rt = Rb + ((lane >> 4) << 2) + rg;
        int grow = rowstart + rt;
        if constexpr (EPI == 1) {
          int t = toklist[grow];
          float wt = wtlist[grow];
          if (t >= 0) {
            size_t ob = (size_t)t * ldOut + colbase;
#pragma unroll
            for (int ni = 0; ni < 4; ++ni)
              atomicAdd(&Fout[ob + ni * 16], acc[mi][ni][rg] + wt * bv[ni]);
          }
        } else {
          size_t ob = (size_t)grow * ldOut + colbase;
#pragma unroll
          for (int ni = 0; ni < 4; ++ni)
            Fout[ob + ni * 16] = acc[mi][ni][rg] + bv[ni];
        }
      }
  }
#undef PHASE
#undef STG_HT
}

// ---------------- host ----------------
extern "C" void kernel_launch(void* const* d_in, const int* in_sizes, int n_in,
                              void* d_out, int out_size, void* d_ws, size_t ws_size,
                              hipStream_t stream) {
  const float* x   = (const float*)d_in[0];
  const float* gw  = (const float*)d_in[1];
  const float* ew1 = (const float*)d_in[2];
  const float* eb1 = (const float*)d_in[3];
  const float* ew2 = (const float*)d_in[4];
  const float* eb2 = (const float*)d_in[5];
  const float* ew3 = (const float*)d_in[6];
  const float* eb3 = (const float*)d_in[7];
  const float* sw1 = (const float*)d_in[8];
  const float* sb1 = (const float*)d_in[9];
  const float* sw2 = (const float*)d_in[10];
  const float* sb2 = (const float*)d_in[11];
  const float* sw3 = (const float*)d_in[12];
  const float* sb3 = (const float*)d_in[13];
  float* out = (float*)d_out;
  (void)ws_size;

  char* ws = (char*)d_ws;
  size_t off = 0;
  auto alloc = [&](size_t bytes) -> void* {
    off = (off + 255) & ~(size_t)255;
    void* p = ws + off;
    off += bytes;
    return p;
  };

  bf16_t* xb    = (bf16_t*)alloc((size_t)TOK * DIMD * 2);
  bf16_t* ew13i = (bf16_t*)alloc((size_t)NEXP * 2 * INTERD * DIMD * 2);
  bf16_t* ew2b  = (bf16_t*)alloc((size_t)NEXP * DIMD * INTERD * 2);
  bf16_t* sw13i = (bf16_t*)alloc((size_t)2 * SINTER * DIMD * 2);
  bf16_t* sw2b  = (bf16_t*)alloc((size_t)DIMD * SINTER * 2);
  // H union: shared Hs (8192x2048) and routed Hg (36864x1024) in disjoint windows
  bf16_t* Hun   = (bf16_t*)alloc((size_t)CAP256 * INTERD * 2);
  bf16_t* Hs    = Hun;
  bf16_t* Hg    = Hun;
  int*   toklist = (int*)alloc(CAP256 * 4);
  float* wtlist  = (float*)alloc(CAP256 * 4);
  int*   offsets = (int*)alloc((NEXP + 1) * 4);
  int*   blkhist = (int*)alloc(HBLK * NEXP * 4);
  int*   blkbase = (int*)alloc(HBLK * NEXP * 4);
  int*   tile_e  = (int*)alloc(512 * 4);
  int*   tile_rs = (int*)alloc(512 * 4);
  int*   tkidx   = (int*)alloc((size_t)TOK * 4 * 4);
  float* tkwt    = (float*)alloc((size_t)TOK * 4 * 4);

  init_kernel<<<(CAP256 + 255) / 256, 256, 0, stream>>>(toklist, wtlist, tile_e, tile_rs);

  cvt_kernel<<<2048, 256, 0, stream>>>(x,   xb,   TOK * DIMD / 4);
  cvt_kernel<<<2048, 256, 0, stream>>>(ew2, ew2b, NEXP * DIMD * INTERD / 4);
  cvt_kernel<<<512,  256, 0, stream>>>(sw2, sw2b, DIMD * SINTER / 4);
  cvt_ileave<<<2048, 256, 0, stream>>>(ew1, ew3, ew13i, NEXP * 2 * INTERD * DIMD / 4, 11);
  cvt_ileave<<<1024, 256, 0, stream>>>(sw1, sw3, sw13i, 2 * SINTER * DIMD / 4, 12);

  gate_kernel<<<TOK / 4, 256, 0, stream>>>(x, gw, tkidx, tkwt);
  hist_kernel<<<HBLK, 256, 0, stream>>>(tkidx, blkhist);
  offs_kernel<<<1, 64, 0, stream>>>(blkhist, offsets, blkbase, tile_e, tile_rs);
  scat_kernel<<<HBLK, 256, 0, stream>>>(tkidx, tkwt, blkbase, toklist, wtlist);

  // shared expert: H = silu(x sw1^T + sb1)*(x sw3^T + sb3); out = H sw2^T + sb2
  gemm8p<false, 0><<<dim3(2 * SINTER / 256, TOK / 256), 512, 0, stream>>>(
      xb, sw13i, sb1, sb3, Hs, nullptr, nullptr, nullptr, nullptr,
      DIMD, SINTER, 0, 0);
  gemm8p<false, 2><<<dim3(DIMD / 256, TOK / 256), 512, 0, stream>>>(
      Hs, sw2b, sb2, nullptr, out, nullptr, nullptr, nullptr, nullptr,
      SINTER, DIMD, 0, 0);

  // routed experts (grouped 256-row tiles; H pre-scaled by route weight)
  gemm8p<true, 0><<<dim3(2 * INTERD / 256, MAXT), 512, 0, stream>>>(
      xb, ew13i, eb1, eb3, Hg, tile_e, tile_rs, toklist, wtlist,
      DIMD, INTERD, (size_t)2 * INTERD * DIMD, INTERD);
  gemm8p<true, 1><<<dim3(DIMD / 256, MAXT), 512, 0, stream>>>(
      Hg, ew2b, eb2, nullptr, out, tile_e, tile_rs, toklist, wtlist,
      INTERD, DIMD, (size_t)DIMD * INTERD, DIMD);
}